// Round 2
// baseline (200.745 us; speedup 1.0000x reference)
//
#include <hip/hip_runtime.h>
#include <hip/hip_bf16.h>

// GAT layer for MI355X (gfx950). FP32 inputs/outputs (per reference dtypes).
//   K1 gat_wh  : Wh = h @ W^T via split-bf16 MFMA (hi*hi + hi*lo + lo*hi),
//                stored TRANSPOSED as two bf16 planes WhT_hi/WhT_lo.
//   K2 gat_f12 : f1[i] = Wh[i,:]·a1, f2[i] = Wh[i,:]·a2 (fp32), pre-scaled log2e.
//   K3 gat_attn: flash-style masked softmax + PV. Rank-1 scores
//                e_ij = lrelu(f1_i+f2_j); p = adj ? exp2(x) : 0 (no max-sub
//                needed, e <= ~7); O = (P @ (Wh_hi+Wh_lo)) / rowsum, with
//                rowsum summed from the SAME bf16-rounded p as the MFMA uses.
//                adj (256 MB int32) is the HBM-bound stream (floor ~41 us).

typedef __bf16 bf16;
typedef __attribute__((ext_vector_type(8))) __bf16 bf16x8;
typedef __attribute__((ext_vector_type(4))) __bf16 bf16x4;
typedef __attribute__((ext_vector_type(4))) float f32x4;

#define N_NODES 8192
#define F_IN 256
#define F_OUT 128
#define LOG2E 1.44269504088896f
#define ALPHA 0.2f

__device__ __forceinline__ void split8(const float* __restrict__ p,
                                       bf16x8& hi, bf16x8& lo) {
    const float4 u = *(const float4*)p;
    const float4 v = *(const float4*)(p + 4);
    float f[8] = {u.x, u.y, u.z, u.w, v.x, v.y, v.z, v.w};
#pragma unroll
    for (int j = 0; j < 8; ++j) {
        const bf16 h = (bf16)f[j];
        hi[j] = h;
        lo[j] = (bf16)(f[j] - (float)h);
    }
}

// ---------------------------------------------------------------------------
// K1: Wh = h @ W^T (M=8192,N=128,K=256) -> WhT_hi/lo[128][8192] (bf16 planes).
// 128 blocks x 256 thr; wave computes 16 rows x 128 cols.
// MFMA lane map (m97-pattern): A row=l&15, k=8*(l>>4)+j ; B col=l&15, same k.
// C/D (m89): col=lane&15, row=4*(lane>>4)+reg.
// ---------------------------------------------------------------------------
__global__ __launch_bounds__(256) void gat_wh(const float* __restrict__ h,
                                              const float* __restrict__ W,
                                              bf16* __restrict__ WhT_hi,
                                              bf16* __restrict__ WhT_lo) {
    const int tid = threadIdx.x;
    const int wv = tid >> 6;
    const int l15 = tid & 15;
    const int g = (tid & 63) >> 4;
    const int rowbase = blockIdx.x * 64 + wv * 16;

    f32x4 acc[8];
    const f32x4 zz = {0.f, 0.f, 0.f, 0.f};
#pragma unroll
    for (int nf = 0; nf < 8; ++nf) acc[nf] = zz;

#pragma unroll
    for (int ks = 0; ks < 8; ++ks) {
        const int k = ks * 32 + g * 8;
        bf16x8 ah, al;
        split8(h + (size_t)(rowbase + l15) * F_IN + k, ah, al);
#pragma unroll
        for (int nf = 0; nf < 8; ++nf) {
            bf16x8 bh, bl;
            split8(W + (size_t)(nf * 16 + l15) * F_IN + k, bh, bl);
            acc[nf] = __builtin_amdgcn_mfma_f32_16x16x32_bf16(ah, bh, acc[nf], 0, 0, 0);
            acc[nf] = __builtin_amdgcn_mfma_f32_16x16x32_bf16(ah, bl, acc[nf], 0, 0, 0);
            acc[nf] = __builtin_amdgcn_mfma_f32_16x16x32_bf16(al, bh, acc[nf], 0, 0, 0);
        }
    }

    // Transposed scattered 2B stores (WhT planes are small; merged in L2).
#pragma unroll
    for (int nf = 0; nf < 8; ++nf)
#pragma unroll
        for (int r = 0; r < 4; ++r) {
            const int row = rowbase + g * 4 + r;
            const int c = nf * 16 + l15;
            const float val = acc[nf][r];
            const bf16 vh = (bf16)val;
            WhT_hi[(size_t)c * N_NODES + row] = vh;
            WhT_lo[(size_t)c * N_NODES + row] = (bf16)(val - (float)vh);
        }
}

// ---------------------------------------------------------------------------
// K2: f1/f2 in fp32 (pre-scaled by log2e). Coalesced column reads of WhT.
// ---------------------------------------------------------------------------
__global__ __launch_bounds__(256) void gat_f12(const bf16* __restrict__ WhT_hi,
                                               const bf16* __restrict__ WhT_lo,
                                               const float* __restrict__ a,
                                               float* __restrict__ f1L,
                                               float* __restrict__ f2L) {
    const int i = blockIdx.x * 256 + threadIdx.x;
    float s1 = 0.f, s2 = 0.f;
#pragma unroll 8
    for (int c = 0; c < F_OUT; ++c) {
        const float wh = (float)WhT_hi[(size_t)c * N_NODES + i] +
                         (float)WhT_lo[(size_t)c * N_NODES + i];
        s1 += wh * a[c];
        s2 += wh * a[F_OUT + c];
    }
    f1L[i] = s1 * LOG2E;
    f2L[i] = s2 * LOG2E;
}

// ---------------------------------------------------------------------------
// K3: fused masked softmax + PV.
// 256 blocks x 512 thr (8 waves); block rows [32b,32b+32), 64 tiles of 128.
// Per tile: prefetch next adj to regs; compute P (bf16) -> dbuf LDS with XOR
// swizzle (row-major [32][256B] would 16-way conflict on ds_read_b128); one
// barrier; wave w MFMAs cols [16w,16w+16): A=P from LDS, B=WhT hi/lo from
// global (L2/L3-hot). Epilogue: 16-lane rowsum reduce -> divide -> fp32 out.
// ---------------------------------------------------------------------------
__global__ __launch_bounds__(512) void gat_attn(const int* __restrict__ adj,
                                                const bf16* __restrict__ WhT_hi,
                                                const bf16* __restrict__ WhT_lo,
                                                const float* __restrict__ f1L,
                                                const float* __restrict__ f2L,
                                                float* __restrict__ out) {
    __shared__ bf16 Pbuf[2][32 * 128];
    __shared__ float rowsum_lds[32];

    const int tid = threadIdx.x;
    const int wv = tid >> 6;        // wave -> output cols [16wv,16wv+16)
    const int l15 = tid & 15;
    const int g = (tid & 63) >> 4;
    const int prow = tid >> 4;      // 0..31: local row this thread fills in P
    const int pcb = (tid & 15) * 4; // col group base; second group at +64
    const int r0 = blockIdx.x * 32;

    const int* adjrow = adj + (size_t)(r0 + prow) * N_NODES;
    const float f1r = f1L[r0 + prow];

    f32x4 acc0 = {0.f, 0.f, 0.f, 0.f};
    f32x4 acc1 = {0.f, 0.f, 0.f, 0.f};
    float rs = 0.f;

    // tile-0 adjacency prefetch (8 ints = 2 x int4 per thread)
    int4 c0 = *(const int4*)(adjrow + pcb);
    int4 c1 = *(const int4*)(adjrow + 64 + pcb);

    const int xw = (prow & 7) << 4; // write-side swizzle (byte XOR)
    const int xr = (l15 & 7) << 4;  // read-side swizzle (row = l15 / l15+16)

    for (int t = 0; t < 64; ++t) {
        // prefetch next tile's adj (consumed next iteration)
        const int tn = (t < 63) ? (t + 1) : 63;
        int4 n0 = *(const int4*)(adjrow + (size_t)tn * 128 + pcb);
        int4 n1 = *(const int4*)(adjrow + (size_t)tn * 128 + 64 + pcb);

        // B fragments (hi/lo) for current tile — L2-resident stream
        const size_t boff = (size_t)(wv * 16 + l15) * N_NODES + t * 128 + g * 8;
        const bf16* bh = WhT_hi + boff;
        const bf16* bl = WhT_lo + boff;
        bf16x8 bh0 = *(const bf16x8*)(bh);
        bf16x8 bh1 = *(const bf16x8*)(bh + 32);
        bf16x8 bh2 = *(const bf16x8*)(bh + 64);
        bf16x8 bh3 = *(const bf16x8*)(bh + 96);
        bf16x8 bl0 = *(const bf16x8*)(bl);
        bf16x8 bl1 = *(const bf16x8*)(bl + 32);
        bf16x8 bl2 = *(const bf16x8*)(bl + 64);
        bf16x8 bl3 = *(const bf16x8*)(bl + 96);

        // P for current tile
        const float4 f2a = *(const float4*)(f2L + t * 128 + pcb);
        const float4 f2b = *(const float4*)(f2L + t * 128 + 64 + pcb);

        auto pcalc = [&](int adjv, float f2v) -> float {
            const float x = f1r + f2v; // already *log2e
            const float e = __builtin_amdgcn_exp2f(fmaxf(x, ALPHA * x));
            return (adjv > 0) ? e : 0.f;
        };
        const bf16x4 pv0 = {(bf16)pcalc(c0.x, f2a.x), (bf16)pcalc(c0.y, f2a.y),
                            (bf16)pcalc(c0.z, f2a.z), (bf16)pcalc(c0.w, f2a.w)};
        const bf16x4 pv1 = {(bf16)pcalc(c1.x, f2b.x), (bf16)pcalc(c1.y, f2b.y),
                            (bf16)pcalc(c1.z, f2b.z), (bf16)pcalc(c1.w, f2b.w)};
        // rowsum from the SAME bf16-rounded weights the MFMA consumes
        rs += ((float)pv0[0] + (float)pv0[1]) + ((float)pv0[2] + (float)pv0[3]) +
              ((float)pv1[0] + (float)pv1[1]) + ((float)pv1[2] + (float)pv1[3]);

        char* pb = (char*)&Pbuf[t & 1][0];
        *(bf16x4*)(pb + ((prow * 256 + pcb * 2) ^ xw)) = pv0;
        *(bf16x4*)(pb + ((prow * 256 + 128 + pcb * 2) ^ xw)) = pv1;

        __syncthreads(); // P[t&1] ready; dbuf => one barrier per tile

        // acc += P[32][128] @ Wh[128][16wv..]
        const char* pr = (const char*)&Pbuf[t & 1][0];
#pragma unroll
        for (int ks = 0; ks < 4; ++ks) {
            const int kb = ks * 64 + g * 16;
            bf16x8 pa0 = *(const bf16x8*)(pr + ((l15 * 256 + kb) ^ xr));
            bf16x8 pa1 = *(const bf16x8*)(pr + (((l15 + 16) * 256 + kb) ^ xr));
            const bf16x8 bhk = (ks == 0) ? bh0 : (ks == 1) ? bh1 : (ks == 2) ? bh2 : bh3;
            const bf16x8 blk = (ks == 0) ? bl0 : (ks == 1) ? bl1 : (ks == 2) ? bl2 : bl3;
            acc0 = __builtin_amdgcn_mfma_f32_16x16x32_bf16(pa0, bhk, acc0, 0, 0, 0);
            acc0 = __builtin_amdgcn_mfma_f32_16x16x32_bf16(pa0, blk, acc0, 0, 0, 0);
            acc1 = __builtin_amdgcn_mfma_f32_16x16x32_bf16(pa1, bhk, acc1, 0, 0, 0);
            acc1 = __builtin_amdgcn_mfma_f32_16x16x32_bf16(pa1, blk, acc1, 0, 0, 0);
        }

        c0 = n0;
        c1 = n1;
    }

    // rowsum: 16 consecutive lanes per row -> 16-wide xor reduce
    rs += __shfl_xor(rs, 1, 16);
    rs += __shfl_xor(rs, 2, 16);
    rs += __shfl_xor(rs, 4, 16);
    rs += __shfl_xor(rs, 8, 16);
    if ((tid & 15) == 0) rowsum_lds[prow] = rs;
    __syncthreads();

    // epilogue: divide, fp32 store. D row = 4*(lane>>4)+reg, col = lane&15.
#pragma unroll
    for (int m = 0; m < 2; ++m)
#pragma unroll
        for (int r = 0; r < 4; ++r) {
            const int lr = m * 16 + g * 4 + r;
            const float v = ((m == 0) ? acc0[r] : acc1[r]) / rowsum_lds[lr];
            out[(size_t)(r0 + lr) * F_OUT + wv * 16 + l15] = v;
        }
}

// ---------------------------------------------------------------------------
extern "C" void kernel_launch(void* const* d_in, const int* in_sizes, int n_in,
                              void* d_out, int out_size, void* d_ws, size_t ws_size,
                              hipStream_t stream) {
    const float* h = (const float*)d_in[0];  // (8192, 256) fp32
    const int* adj = (const int*)d_in[1];    // (8192, 8192) int32
    const float* W = (const float*)d_in[2];  // (128, 256) fp32
    const float* a = (const float*)d_in[3];  // (1, 256) fp32
    float* out = (float*)d_out;              // (8192, 128) fp32

    char* ws = (char*)d_ws;
    bf16* WhT_hi = (bf16*)ws;                                  // 2 MB
    bf16* WhT_lo = (bf16*)(ws + (size_t)2 * 1024 * 1024);      // 2 MB
    float* f1L = (float*)(ws + (size_t)4 * 1024 * 1024);       // 32 KB
    float* f2L = f1L + N_NODES;                                // 32 KB

    gat_wh<<<128, 256, 0, stream>>>(h, W, WhT_hi, WhT_lo);
    gat_f12<<<N_NODES / 256, 256, 0, stream>>>(WhT_hi, WhT_lo, a, f1L, f2L);
    gat_attn<<<N_NODES / 32, 512, 0, stream>>>(adj, WhT_hi, WhT_lo, f1L, f2L, out);
}

// Round 3
// 177.558 us; speedup vs baseline: 1.1306x; 1.1306x over previous
//
#include <hip/hip_runtime.h>
#include <hip/hip_bf16.h>

// GAT layer for MI355X (gfx950). FP32 inputs/outputs (per reference dtypes).
//   K1 gat_wh  : Wh = h @ W^T via split-bf16 MFMA (hi*hi + hi*lo + lo*hi),
//                stored TRANSPOSED as two bf16 planes WhT_hi/WhT_lo.
//   K2 gat_f12 : f1[i] = Wh[i,:]·a1, f2[i] = Wh[i,:]·a2 (fp32), pre-scaled log2e.
//   K3 gat_attn: flash-style masked softmax + PV, software-pipelined:
//                adj prefetched 3 tiles ahead, B/f2 1 tile ahead, raw s_barrier
//                (NO vmcnt drain — the round-2 kernel lost 2x+ to the
//                __syncthreads vmcnt(0) drain killing the adj prefetch).

typedef __bf16 bf16;
typedef __attribute__((ext_vector_type(8))) __bf16 bf16x8;
typedef __attribute__((ext_vector_type(4))) __bf16 bf16x4;
typedef __attribute__((ext_vector_type(4))) float f32x4;

#define N_NODES 8192
#define F_IN 256
#define F_OUT 128
#define LOG2E 1.44269504088896f
#define ALPHA 0.2f

__device__ __forceinline__ void split8(const float* __restrict__ p,
                                       bf16x8& hi, bf16x8& lo) {
    const float4 u = *(const float4*)p;
    const float4 v = *(const float4*)(p + 4);
    float f[8] = {u.x, u.y, u.z, u.w, v.x, v.y, v.z, v.w};
#pragma unroll
    for (int j = 0; j < 8; ++j) {
        const bf16 h = (bf16)f[j];
        hi[j] = h;
        lo[j] = (bf16)(f[j] - (float)h);
    }
}

// ---------------------------------------------------------------------------
// K1: Wh = h @ W^T (M=8192,N=128,K=256) -> WhT_hi/lo[128][8192] (bf16 planes).
// (unchanged from round 2 — correct; optimize only if profile says so)
// ---------------------------------------------------------------------------
__global__ __launch_bounds__(256) void gat_wh(const float* __restrict__ h,
                                              const float* __restrict__ W,
                                              bf16* __restrict__ WhT_hi,
                                              bf16* __restrict__ WhT_lo) {
    const int tid = threadIdx.x;
    const int wv = tid >> 6;
    const int l15 = tid & 15;
    const int g = (tid & 63) >> 4;
    const int rowbase = blockIdx.x * 64 + wv * 16;

    f32x4 acc[8];
    const f32x4 zz = {0.f, 0.f, 0.f, 0.f};
#pragma unroll
    for (int nf = 0; nf < 8; ++nf) acc[nf] = zz;

#pragma unroll
    for (int ks = 0; ks < 8; ++ks) {
        const int k = ks * 32 + g * 8;
        bf16x8 ah, al;
        split8(h + (size_t)(rowbase + l15) * F_IN + k, ah, al);
#pragma unroll
        for (int nf = 0; nf < 8; ++nf) {
            bf16x8 bh, bl;
            split8(W + (size_t)(nf * 16 + l15) * F_IN + k, bh, bl);
            acc[nf] = __builtin_amdgcn_mfma_f32_16x16x32_bf16(ah, bh, acc[nf], 0, 0, 0);
            acc[nf] = __builtin_amdgcn_mfma_f32_16x16x32_bf16(ah, bl, acc[nf], 0, 0, 0);
            acc[nf] = __builtin_amdgcn_mfma_f32_16x16x32_bf16(al, bh, acc[nf], 0, 0, 0);
        }
    }

#pragma unroll
    for (int nf = 0; nf < 8; ++nf)
#pragma unroll
        for (int r = 0; r < 4; ++r) {
            const int row = rowbase + g * 4 + r;
            const int c = nf * 16 + l15;
            const float val = acc[nf][r];
            const bf16 vh = (bf16)val;
            WhT_hi[(size_t)c * N_NODES + row] = vh;
            WhT_lo[(size_t)c * N_NODES + row] = (bf16)(val - (float)vh);
        }
}

// ---------------------------------------------------------------------------
// K2: f1/f2 in fp32 (pre-scaled by log2e). 64-thr blocks x 128 -> 128 CUs
// (round-2 used 32 blocks = 32 CUs).
// ---------------------------------------------------------------------------
__global__ __launch_bounds__(64) void gat_f12(const bf16* __restrict__ WhT_hi,
                                              const bf16* __restrict__ WhT_lo,
                                              const float* __restrict__ a,
                                              float* __restrict__ f1L,
                                              float* __restrict__ f2L) {
    const int i = blockIdx.x * 64 + threadIdx.x;
    float s1 = 0.f, s2 = 0.f;
#pragma unroll 8
    for (int c = 0; c < F_OUT; ++c) {
        const float wh = (float)WhT_hi[(size_t)c * N_NODES + i] +
                         (float)WhT_lo[(size_t)c * N_NODES + i];
        s1 += wh * a[c];
        s2 += wh * a[F_OUT + c];
    }
    f1L[i] = s1 * LOG2E;
    f2L[i] = s2 * LOG2E;
}

// ---------------------------------------------------------------------------
// K3: fused masked softmax + PV, deep-pipelined.
// 256 blocks x 512 thr (8 waves); block rows [32b,32b+32), 64 tiles of 128.
// Pipeline: adj 3 tiles ahead (HBM ~900cy), B-frags + f2 1 tile ahead (L2/L3).
// One RAW barrier per tile (lgkmcnt-only wait) + LDS double buffer: loads
// stay in flight across the barrier; compiler inserts counted vmcnt at use.
// ---------------------------------------------------------------------------
__global__ __launch_bounds__(512) void gat_attn(const int* __restrict__ adj,
                                                const bf16* __restrict__ WhT_hi,
                                                const bf16* __restrict__ WhT_lo,
                                                const float* __restrict__ f1L,
                                                const float* __restrict__ f2L,
                                                float* __restrict__ out) {
    __shared__ bf16 Pbuf[2][32 * 128];
    __shared__ float rowsum_lds[32];

    const int tid = threadIdx.x;
    const int wv = tid >> 6;        // wave -> output cols [16wv,16wv+16)
    const int l15 = tid & 15;
    const int g = (tid & 63) >> 4;
    const int prow = tid >> 4;      // 0..31: local row this thread fills in P
    const int pcb = (tid & 15) * 4; // col group base; second group at +64
    const int r0 = blockIdx.x * 32;

    const int* adjrow = adj + (size_t)(r0 + prow) * N_NODES;
    const float f1r = f1L[r0 + prow];

    f32x4 acc0 = {0.f, 0.f, 0.f, 0.f};
    f32x4 acc1 = {0.f, 0.f, 0.f, 0.f};
    float rs = 0.f;

    const int xw = (prow & 7) << 4; // write-side swizzle (byte XOR)
    const int xr = (l15 & 7) << 4;  // read-side swizzle

    // ---- prologue: adj tiles 0..2, B tile 0, f2 tile 0 ----
    int4 c00 = *(const int4*)(adjrow + pcb);
    int4 c01 = *(const int4*)(adjrow + 64 + pcb);
    int4 c10 = *(const int4*)(adjrow + 128 + pcb);
    int4 c11 = *(const int4*)(adjrow + 128 + 64 + pcb);
    int4 c20 = *(const int4*)(adjrow + 256 + pcb);
    int4 c21 = *(const int4*)(adjrow + 256 + 64 + pcb);

    const size_t bbase = (size_t)(wv * 16 + l15) * N_NODES + g * 8;
    bf16x8 bh0 = *(const bf16x8*)(WhT_hi + bbase);
    bf16x8 bh1 = *(const bf16x8*)(WhT_hi + bbase + 32);
    bf16x8 bh2 = *(const bf16x8*)(WhT_hi + bbase + 64);
    bf16x8 bh3 = *(const bf16x8*)(WhT_hi + bbase + 96);
    bf16x8 bl0 = *(const bf16x8*)(WhT_lo + bbase);
    bf16x8 bl1 = *(const bf16x8*)(WhT_lo + bbase + 32);
    bf16x8 bl2 = *(const bf16x8*)(WhT_lo + bbase + 64);
    bf16x8 bl3 = *(const bf16x8*)(WhT_lo + bbase + 96);

    float4 fa = *(const float4*)(f2L + pcb);
    float4 fb = *(const float4*)(f2L + 64 + pcb);

    for (int t = 0; t < 64; ++t) {
        const int t3 = (t + 3 < 64) ? t + 3 : 63;
        const int t1 = (t + 1 < 64) ? t + 1 : 63;

        // issue adj[t+3] (HBM stream; ~3 tiles of lead time)
        int4 p0 = *(const int4*)(adjrow + (size_t)t3 * 128 + pcb);
        int4 p1 = *(const int4*)(adjrow + (size_t)t3 * 128 + 64 + pcb);

        // issue B[t+1] (hi/lo) and f2[t+1]
        const size_t nboff = bbase + (size_t)t1 * 128;
        bf16x8 nbh0 = *(const bf16x8*)(WhT_hi + nboff);
        bf16x8 nbh1 = *(const bf16x8*)(WhT_hi + nboff + 32);
        bf16x8 nbh2 = *(const bf16x8*)(WhT_hi + nboff + 64);
        bf16x8 nbh3 = *(const bf16x8*)(WhT_hi + nboff + 96);
        bf16x8 nbl0 = *(const bf16x8*)(WhT_lo + nboff);
        bf16x8 nbl1 = *(const bf16x8*)(WhT_lo + nboff + 32);
        bf16x8 nbl2 = *(const bf16x8*)(WhT_lo + nboff + 64);
        bf16x8 nbl3 = *(const bf16x8*)(WhT_lo + nboff + 96);
        float4 nfa = *(const float4*)(f2L + t1 * 128 + pcb);
        float4 nfb = *(const float4*)(f2L + t1 * 128 + 64 + pcb);

        // ---- P for current tile (adj regs loaded 3 tiles ago) ----
        auto pcalc = [&](int adjv, float f2v) -> float {
            const float x = f1r + f2v; // already *log2e
            const float e = __builtin_amdgcn_exp2f(fmaxf(x, ALPHA * x));
            return (adjv > 0) ? e : 0.f;
        };
        const bf16x4 pv0 = {(bf16)pcalc(c00.x, fa.x), (bf16)pcalc(c00.y, fa.y),
                            (bf16)pcalc(c00.z, fa.z), (bf16)pcalc(c00.w, fa.w)};
        const bf16x4 pv1 = {(bf16)pcalc(c01.x, fb.x), (bf16)pcalc(c01.y, fb.y),
                            (bf16)pcalc(c01.z, fb.z), (bf16)pcalc(c01.w, fb.w)};
        // rowsum from the SAME bf16-rounded weights the MFMA consumes
        rs += ((float)pv0[0] + (float)pv0[1]) + ((float)pv0[2] + (float)pv0[3]) +
              ((float)pv1[0] + (float)pv1[1]) + ((float)pv1[2] + (float)pv1[3]);

        char* pb = (char*)&Pbuf[t & 1][0];
        *(bf16x4*)(pb + ((prow * 256 + pcb * 2) ^ xw)) = pv0;
        *(bf16x4*)(pb + ((prow * 256 + 128 + pcb * 2) ^ xw)) = pv1;

        // raw barrier: wait LDS only — global prefetches stay in flight
        asm volatile("s_waitcnt lgkmcnt(0)" ::: "memory");
        __builtin_amdgcn_s_barrier();
        asm volatile("" ::: "memory");
        __builtin_amdgcn_sched_barrier(0);

        // ---- acc += P[32][128] @ Wh[128][16wv..] ----
        const char* pr = (const char*)&Pbuf[t & 1][0];
#pragma unroll
        for (int ks = 0; ks < 4; ++ks) {
            const int kb = ks * 64 + g * 16;
            bf16x8 pa0 = *(const bf16x8*)(pr + ((l15 * 256 + kb) ^ xr));
            bf16x8 pa1 = *(const bf16x8*)(pr + (((l15 + 16) * 256 + kb) ^ xr));
            const bf16x8 bhk = (ks == 0) ? bh0 : (ks == 1) ? bh1 : (ks == 2) ? bh2 : bh3;
            const bf16x8 blk = (ks == 0) ? bl0 : (ks == 1) ? bl1 : (ks == 2) ? bl2 : bl3;
            acc0 = __builtin_amdgcn_mfma_f32_16x16x32_bf16(pa0, bhk, acc0, 0, 0, 0);
            acc0 = __builtin_amdgcn_mfma_f32_16x16x32_bf16(pa0, blk, acc0, 0, 0, 0);
            acc1 = __builtin_amdgcn_mfma_f32_16x16x32_bf16(pa1, bhk, acc1, 0, 0, 0);
            acc1 = __builtin_amdgcn_mfma_f32_16x16x32_bf16(pa1, blk, acc1, 0, 0, 0);
        }

        // ---- rotate pipeline registers ----
        c00 = c10; c01 = c11;
        c10 = c20; c11 = c21;
        c20 = p0;  c21 = p1;
        bh0 = nbh0; bh1 = nbh1; bh2 = nbh2; bh3 = nbh3;
        bl0 = nbl0; bl1 = nbl1; bl2 = nbl2; bl3 = nbl3;
        fa = nfa; fb = nfb;
    }

    // rowsum: 16 consecutive lanes per row -> 16-wide xor reduce
    rs += __shfl_xor(rs, 1, 16);
    rs += __shfl_xor(rs, 2, 16);
    rs += __shfl_xor(rs, 4, 16);
    rs += __shfl_xor(rs, 8, 16);
    if ((tid & 15) == 0) rowsum_lds[prow] = rs;
    __syncthreads();

    // epilogue: divide, fp32 store. D row = 4*(lane>>4)+reg, col = lane&15.
#pragma unroll
    for (int m = 0; m < 2; ++m)
#pragma unroll
        for (int r = 0; r < 4; ++r) {
            const int lr = m * 16 + g * 4 + r;
            const float v = ((m == 0) ? acc0[r] : acc1[r]) / rowsum_lds[lr];
            out[(size_t)(r0 + lr) * F_OUT + wv * 16 + l15] = v;
        }
}

// ---------------------------------------------------------------------------
extern "C" void kernel_launch(void* const* d_in, const int* in_sizes, int n_in,
                              void* d_out, int out_size, void* d_ws, size_t ws_size,
                              hipStream_t stream) {
    const float* h = (const float*)d_in[0];  // (8192, 256) fp32
    const int* adj = (const int*)d_in[1];    // (8192, 8192) int32
    const float* W = (const float*)d_in[2];  // (128, 256) fp32
    const float* a = (const float*)d_in[3];  // (1, 256) fp32
    float* out = (float*)d_out;              // (8192, 128) fp32

    char* ws = (char*)d_ws;
    bf16* WhT_hi = (bf16*)ws;                                  // 2 MB
    bf16* WhT_lo = (bf16*)(ws + (size_t)2 * 1024 * 1024);      // 2 MB
    float* f1L = (float*)(ws + (size_t)4 * 1024 * 1024);       // 32 KB
    float* f2L = f1L + N_NODES;                                // 32 KB

    gat_wh<<<128, 256, 0, stream>>>(h, W, WhT_hi, WhT_lo);
    gat_f12<<<N_NODES / 64, 64, 0, stream>>>(WhT_hi, WhT_lo, a, f1L, f2L);
    gat_attn<<<N_NODES / 32, 512, 0, stream>>>(adj, WhT_hi, WhT_lo, f1L, f2L, out);
}